// Round 17
// baseline (34.910 us; speedup 1.0000x reference)
//
#include <hip/hip_runtime.h>

#pragma clang fp contract(off)

typedef unsigned long long u64;
typedef float f4 __attribute__((ext_vector_type(4)));

#define TOPK 5
#define WAVES 4   // waves {0,1} -> gt0, waves {2,3} -> gt1 (R12/R16 structure)

// branchless compare-exchange on u64 keys (ascending)
#define CE(x, y) do { const u64 _a = (x), _b = (y); const bool _l = _b < _a; \
                      (x) = _l ? _b : _a; (y) = _l ? _a : _b; } while (0)

// Markstein-refined division (bit-exact vs reference: absmax 0.0 in R3-R16)
__device__ __forceinline__ float fast_div(float a, float b) {
    float r = __builtin_amdgcn_rcpf(b);
    r = fmaf(fmaf(-b, r, 1.0f), r, r);
    float q = a * r;
    q = fmaf(fmaf(-b, q, a), r, q);
    return q;
}

__device__ __forceinline__ u64 eval_key(const f4 pb, const f4 gb,
                                        const float g_area, const int p) {
    const float area_p = (pb.z - pb.x) * (pb.w - pb.y);
    const float cost_bbox = fabsf(pb.x - gb.x) + fabsf(pb.y - gb.y)
                          + fabsf(pb.z - gb.z) + fabsf(pb.w - gb.w);
    const float ltx = fmaxf(pb.x, gb.x), lty = fmaxf(pb.y, gb.y);
    const float rbx = fminf(pb.z, gb.z), rby = fminf(pb.w, gb.w);
    const float iw = fmaxf(rbx - ltx, 0.0f), ih = fmaxf(rby - lty, 0.0f);
    const float inter = iw * ih;
    const float uni = area_p + g_area - inter;
    const float iou = fast_div(inter, uni);
    const float ex1 = fminf(pb.x, gb.x), ey1 = fminf(pb.y, gb.y);
    const float ex2 = fmaxf(pb.z, gb.z), ey2 = fmaxf(pb.w, gb.w);
    const float area_e = (ex2 - ex1) * (ey2 - ey1);
    const float giou = iou - fast_div(area_e - uni, area_e);
    const float cost = cost_bbox + (1.0f - giou);
    return ((u64)__float_as_uint(cost) << 32) | (unsigned)p;
}

__global__ __launch_bounds__(64 * WAVES) void matcher_topk_kernel(
    const float* __restrict__ pred_box,  // [B, NP, 4]
    const float* __restrict__ gt_box,    // [B, NG, 4]
    int* __restrict__ out_pred,          // [B, NG*TOPK]
    int* __restrict__ out_gt,            // [B, NG*TOPK]
    int B, int NP, int NG)
{
    const int pairsPerB = (NG + 1) >> 1;
    const int tp = blockIdx.x;               // one block per (b, gt-pair)
    const int b  = tp / pairsPerB;
    const int j  = tp - b * pairsPerB;
    const int m0 = 2 * j;
    const bool has1 = (m0 + 1 < NG);

    const int wid  = threadIdx.x >> 6;
    const int lane = threadIdx.x & 63;
    const int myGt = wid >> 1;               // 0 or 1
    const int half = wid & 1;                // pred half

    const f4 gb = ((const f4*)gt_box)[b * NG + (myGt ? (has1 ? m0 + 1 : m0) : m0)];
    const float g_area = (gb.z - gb.x) * (gb.w - gb.y);

    const int NPm1  = NP - 1;
    const int hN    = (NP + 1) >> 1;
    const int start = half ? hN : 0;
    const int pend  = half ? NP : hN;
    // 10 groups of 256 preds per wave (2500/half); static schedule (NP=5000).

    u64 k0 = ~0ULL, k1 = ~0ULL, k2 = ~0ULL, k3 = ~0ULL, k4 = ~0ULL;

    const f4* pbase = (const f4*)pred_box + (size_t)b * NP;

// FAST load (non-tail): one address, offset-folded immediates
#define GLOADF(g, rA, rB, rC, rD) do {                                          \
    const f4* _p = pbase + (start + ((g) << 8) + lane);                         \
    asm volatile("global_load_dwordx4 %0, %1, off"             : "=v"(rA) : "v"(_p)); \
    asm volatile("global_load_dwordx4 %0, %1, off offset:1024" : "=v"(rB) : "v"(_p)); \
    asm volatile("global_load_dwordx4 %0, %1, off offset:2048" : "=v"(rC) : "v"(_p)); \
    asm volatile("global_load_dwordx4 %0, %1, off offset:3072" : "=v"(rD) : "v"(_p)); \
} while (0)

// SAFE load (tail group): per-sub clamp (dup reads of last pred; keys masked)
#define GLOADS(g, rA, rB, rC, rD) do {                                          \
    const int _i = start + ((g) << 8) + lane;                                   \
    const f4* _p0 = pbase + min(_i,       NPm1);                                \
    const f4* _p1 = pbase + min(_i + 64,  NPm1);                                \
    const f4* _p2 = pbase + min(_i + 128, NPm1);                                \
    const f4* _p3 = pbase + min(_i + 192, NPm1);                                \
    asm volatile("global_load_dwordx4 %0, %1, off" : "=v"(rA) : "v"(_p0));      \
    asm volatile("global_load_dwordx4 %0, %1, off" : "=v"(rB) : "v"(_p1));      \
    asm volatile("global_load_dwordx4 %0, %1, off" : "=v"(rC) : "v"(_p2));      \
    asm volatile("global_load_dwordx4 %0, %1, off" : "=v"(rD) : "v"(_p3));      \
} while (0)

// counted wait + sched fence (rule #18)
#define W(n) do {                                         \
    asm volatile("s_waitcnt vmcnt(" #n ")");              \
    __builtin_amdgcn_sched_barrier(0);                    \
} while (0)

// 4 evals (ILP) -> (tail: mask) -> sort4 -> bitonic lower-5 merge into top5
#define PROCG(g, TAIL, rA, rB, rC, rD) do {                                  \
    const int _i0 = start + ((g) << 8) + lane;                               \
    u64 kA = eval_key(rA, gb, g_area, _i0);                                  \
    u64 kB = eval_key(rB, gb, g_area, _i0 + 64);                             \
    u64 kC = eval_key(rC, gb, g_area, _i0 + 128);                            \
    u64 kD = eval_key(rD, gb, g_area, _i0 + 192);                            \
    if (TAIL) {                                                              \
        kA = (_i0       < pend) ? kA : ~0ULL;                                \
        kB = (_i0 + 64  < pend) ? kB : ~0ULL;                                \
        kC = (_i0 + 128 < pend) ? kC : ~0ULL;                                \
        kD = (_i0 + 192 < pend) ? kD : ~0ULL;                                \
    }                                                                        \
    CE(kA, kB); CE(kC, kD); CE(kA, kC); CE(kB, kD); CE(kB, kC);              \
    u64 n0 = k0;                                                             \
    u64 n1 = k1 < kD ? k1 : kD;                                              \
    u64 n2 = k2 < kC ? k2 : kC;                                              \
    u64 n3 = k3 < kB ? k3 : kB;                                              \
    u64 n4 = k4 < kA ? k4 : kA;                                              \
    CE(n0, n1); CE(n3, n4); CE(n2, n4); CE(n2, n3); CE(n1, n4);              \
    CE(n0, n3); CE(n0, n2); CE(n1, n3); CE(n1, n2);                          \
    k0 = n0; k1 = n1; k2 = n2; k3 = n3; k4 = n4;                             \
} while (0)

    // FOUR buffers -> each group's loads age THREE compute phases before use
    f4 xA, xB, xC, xD;
    f4 yA, yB, yC, yD;
    f4 zA, zB, zC, zD;
    f4 wA, wB, wC, wD;

    // static 10-group, depth-4 schedule (16 loads in flight steady-state)
    GLOADF(0, xA, xB, xC, xD);
    GLOADF(1, yA, yB, yC, yD);
    GLOADF(2, zA, zB, zC, zD);
    GLOADF(3, wA, wB, wC, wD);

    W(12); PROCG(0, false, xA, xB, xC, xD); GLOADF(4, xA, xB, xC, xD);
    W(12); PROCG(1, false, yA, yB, yC, yD); GLOADF(5, yA, yB, yC, yD);
    W(12); PROCG(2, false, zA, zB, zC, zD); GLOADF(6, zA, zB, zC, zD);
    W(12); PROCG(3, false, wA, wB, wC, wD); GLOADF(7, wA, wB, wC, wD);
    W(12); PROCG(4, false, xA, xB, xC, xD); GLOADF(8, xA, xB, xC, xD);
    W(12); PROCG(5, false, yA, yB, yC, yD); GLOADS(9, yA, yB, yC, yD);
    W(12); PROCG(6, false, zA, zB, zC, zD);
    W(8);  PROCG(7, false, wA, wB, wC, wD);
    W(4);  PROCG(8, false, xA, xB, xC, xD);
    W(0);  PROCG(9, true,  yA, yB, yC, yD);
    // nothing in flight after W(0) -> no latent-write hazard (R11 lesson):
    // every issued load is consumed before its buffer is reused or we exit

#undef GLOADF
#undef GLOADS
#undef W
#undef PROCG

    // wave butterfly: merge sorted 5-lists across all 64 lanes
    #pragma unroll
    for (int off = 1; off < 64; off <<= 1) {
        const u64 b0 = __shfl_xor(k0, off);
        const u64 b1 = __shfl_xor(k1, off);
        const u64 b2 = __shfl_xor(k2, off);
        const u64 b3 = __shfl_xor(k3, off);
        const u64 b4 = __shfl_xor(k4, off);
        u64 m0_ = k0 < b4 ? k0 : b4;
        u64 m1_ = k1 < b3 ? k1 : b3;
        u64 m2_ = k2 < b2 ? k2 : b2;
        u64 m3_ = k3 < b1 ? k3 : b1;
        u64 m4_ = k4 < b0 ? k4 : b0;
        CE(m0_, m1_); CE(m3_, m4_); CE(m2_, m4_); CE(m2_, m3_); CE(m1_, m4_);
        CE(m0_, m3_); CE(m0_, m2_); CE(m1_, m3_); CE(m1_, m2_);
        k0 = m0_; k1 = m1_; k2 = m2_; k3 = m3_; k4 = m4_;
    }

    // cross-wave merge via LDS: per gt, 2 sorted 5-lists -> final 5
    __shared__ u64 lds[WAVES][TOPK];
    if (lane == 0) {
        lds[wid][0] = k0; lds[wid][1] = k1; lds[wid][2] = k2;
        lds[wid][3] = k3; lds[wid][4] = k4;
    }
    __syncthreads();

    if (threadIdx.x < 2) {
        const int which = threadIdx.x;       // gt0 / gt1
        if (which == 0 || has1) {
            const int mm = m0 + which;
            int h0 = 0, h1 = 0;
            const int base = (b * NG + mm) * TOPK;
            #pragma unroll
            for (int r = 0; r < TOPK; ++r) {
                const u64 v0 = lds[which * 2][h0];
                const u64 v1 = lds[which * 2 + 1][h1];
                const bool t = v0 < v1;
                const u64 best = t ? v0 : v1;
                h0 += t; h1 += !t;
                out_pred[base + r] = (int)(unsigned)(best & 0xFFFFFFFFu);
                out_gt[base + r]   = mm;
            }
        }
    }
}

extern "C" void kernel_launch(void* const* d_in, const int* in_sizes, int n_in,
                              void* d_out, int out_size, void* d_ws, size_t ws_size,
                              hipStream_t stream) {
    const float* pred_box = (const float*)d_in[0];   // [B, NP, 4]
    const float* gt_box   = (const float*)d_in[2];   // [B, NG, 4]

    const int NP = 5000;
    const int B  = in_sizes[1] / NP;                 // pred_obj is [B, NP]
    const int NG = in_sizes[3] / B;                  // gt_obj is [B, NG]

    int* out_pred = (int*)d_out;
    int* out_gt   = out_pred + B * NG * TOPK;

    const int pairsPerB = (NG + 1) >> 1;
    const int blocks = B * pairsPerB;                // one block per gt-pair
    hipLaunchKernelGGL(matcher_topk_kernel, dim3(blocks), dim3(64 * WAVES), 0, stream,
                       pred_box, gt_box, out_pred, out_gt, B, NP, NG);
}

// Round 18
// 34.764 us; speedup vs baseline: 1.0042x; 1.0042x over previous
//
#include <hip/hip_runtime.h>

#pragma clang fp contract(off)

typedef unsigned long long u64;
typedef float f4 __attribute__((ext_vector_type(4)));

#define TOPK 5
#define WAVES 4   // waves {0,1} -> gt0, waves {2,3} -> gt1

// branchless compare-exchange on u64 keys (ascending)
#define CE(x, y) do { const u64 _a = (x), _b = (y); const bool _l = _b < _a; \
                      (x) = _l ? _b : _a; (y) = _l ? _a : _b; } while (0)

// Markstein-refined division (bit-exact vs reference: absmax 0.0 in R3-R17)
__device__ __forceinline__ float fast_div(float a, float b) {
    float r = __builtin_amdgcn_rcpf(b);
    r = fmaf(fmaf(-b, r, 1.0f), r, r);
    float q = a * r;
    q = fmaf(fmaf(-b, q, a), r, q);
    return q;
}

__device__ __forceinline__ u64 eval_key(const f4 pb, const f4 gb,
                                        const float g_area, const int p) {
    const float area_p = (pb.z - pb.x) * (pb.w - pb.y);
    const float cost_bbox = fabsf(pb.x - gb.x) + fabsf(pb.y - gb.y)
                          + fabsf(pb.z - gb.z) + fabsf(pb.w - gb.w);
    const float ltx = fmaxf(pb.x, gb.x), lty = fmaxf(pb.y, gb.y);
    const float rbx = fminf(pb.z, gb.z), rby = fminf(pb.w, gb.w);
    const float iw = fmaxf(rbx - ltx, 0.0f), ih = fmaxf(rby - lty, 0.0f);
    const float inter = iw * ih;
    const float uni = area_p + g_area - inter;
    const float iou = fast_div(inter, uni);
    const float ex1 = fminf(pb.x, gb.x), ey1 = fminf(pb.y, gb.y);
    const float ex2 = fmaxf(pb.z, gb.z), ey2 = fmaxf(pb.w, gb.w);
    const float area_e = (ex2 - ex1) * (ey2 - ey1);
    const float giou = iou - fast_div(area_e - uni, area_e);
    const float cost = cost_bbox + (1.0f - giou);
    return ((u64)__float_as_uint(cost) << 32) | (unsigned)p;
}

__global__ __launch_bounds__(64 * WAVES) void matcher_topk_kernel(
    const float* __restrict__ pred_box,  // [B, NP, 4]
    const float* __restrict__ gt_box,    // [B, NG, 4]
    int* __restrict__ out_pred,          // [B, NG*TOPK]
    int* __restrict__ out_gt,            // [B, NG*TOPK]
    int B, int NP, int NG)
{
    const int pairsPerB = (NG + 1) >> 1;
    const int tp = blockIdx.x;               // one block per (b, gt-pair)
    const int b  = tp / pairsPerB;
    const int j  = tp - b * pairsPerB;
    const int m0 = 2 * j;
    const bool has1 = (m0 + 1 < NG);

    const int wid  = threadIdx.x >> 6;
    const int lane = threadIdx.x & 63;
    const int myGt = wid >> 1;               // 0 or 1
    const int half = wid & 1;                // pred half

    const f4 gb = ((const f4*)gt_box)[b * NG + (myGt ? (has1 ? m0 + 1 : m0) : m0)];
    const float g_area = (gb.z - gb.x) * (gb.w - gb.y);

    const int NPm1  = NP - 1;
    const int hN    = (NP + 1) >> 1;
    const int start = half ? hN : 0;
    const int pend  = half ? NP : hN;
    // 10 groups of 256 preds per wave (2500/half); static schedule (NP=5000).

    u64 k0 = ~0ULL, k1 = ~0ULL, k2 = ~0ULL, k3 = ~0ULL, k4 = ~0ULL;

    const f4* pbase = (const f4*)pred_box + (size_t)b * NP;

// FAST load (non-tail): one address, offset-folded immediates
#define GLOADF(g, rA, rB, rC, rD) do {                                          \
    const f4* _p = pbase + (start + ((g) << 8) + lane);                         \
    asm volatile("global_load_dwordx4 %0, %1, off"             : "=v"(rA) : "v"(_p)); \
    asm volatile("global_load_dwordx4 %0, %1, off offset:1024" : "=v"(rB) : "v"(_p)); \
    asm volatile("global_load_dwordx4 %0, %1, off offset:2048" : "=v"(rC) : "v"(_p)); \
    asm volatile("global_load_dwordx4 %0, %1, off offset:3072" : "=v"(rD) : "v"(_p)); \
} while (0)

// SAFE load (tail group): per-sub clamp (dup reads of last pred; keys masked)
#define GLOADS(g, rA, rB, rC, rD) do {                                          \
    const int _i = start + ((g) << 8) + lane;                                   \
    const f4* _p0 = pbase + min(_i,       NPm1);                                \
    const f4* _p1 = pbase + min(_i + 64,  NPm1);                                \
    const f4* _p2 = pbase + min(_i + 128, NPm1);                                \
    const f4* _p3 = pbase + min(_i + 192, NPm1);                                \
    asm volatile("global_load_dwordx4 %0, %1, off" : "=v"(rA) : "v"(_p0));      \
    asm volatile("global_load_dwordx4 %0, %1, off" : "=v"(rB) : "v"(_p1));      \
    asm volatile("global_load_dwordx4 %0, %1, off" : "=v"(rC) : "v"(_p2));      \
    asm volatile("global_load_dwordx4 %0, %1, off" : "=v"(rD) : "v"(_p3));      \
} while (0)

// counted wait + sched fence (rule #18) — now only ONE per 2 groups
#define W(n) do {                                         \
    asm volatile("s_waitcnt vmcnt(" #n ")");              \
    __builtin_amdgcn_sched_barrier(0);                    \
} while (0)

// 4 evals (ILP) -> (tail: mask) -> sort4 -> bitonic lower-5 merge into top5
#define PROCG(g, TAIL, rA, rB, rC, rD) do {                                  \
    const int _i0 = start + ((g) << 8) + lane;                               \
    u64 kA = eval_key(rA, gb, g_area, _i0);                                  \
    u64 kB = eval_key(rB, gb, g_area, _i0 + 64);                             \
    u64 kC = eval_key(rC, gb, g_area, _i0 + 128);                            \
    u64 kD = eval_key(rD, gb, g_area, _i0 + 192);                            \
    if (TAIL) {                                                              \
        kA = (_i0       < pend) ? kA : ~0ULL;                                \
        kB = (_i0 + 64  < pend) ? kB : ~0ULL;                                \
        kC = (_i0 + 128 < pend) ? kC : ~0ULL;                                \
        kD = (_i0 + 192 < pend) ? kD : ~0ULL;                                \
    }                                                                        \
    CE(kA, kB); CE(kC, kD); CE(kA, kC); CE(kB, kD); CE(kB, kC);              \
    u64 n0 = k0;                                                             \
    u64 n1 = k1 < kD ? k1 : kD;                                              \
    u64 n2 = k2 < kC ? k2 : kC;                                              \
    u64 n3 = k3 < kB ? k3 : kB;                                              \
    u64 n4 = k4 < kA ? k4 : kA;                                              \
    CE(n0, n1); CE(n3, n4); CE(n2, n4); CE(n2, n3); CE(n1, n4);              \
    CE(n0, n3); CE(n0, n2); CE(n1, n3); CE(n1, n2);                          \
    k0 = n0; k1 = n1; k2 = n2; k3 = n3; k4 = n4;                             \
} while (0)

    // four buffers, TWO groups processed per phase (8 eval chains of ILP,
    // one scheduling stop per phase instead of per group)
    f4 xA, xB, xC, xD;
    f4 yA, yB, yC, yD;
    f4 zA, zB, zC, zD;
    f4 uA, uB, uC, uD;

    GLOADF(0, xA, xB, xC, xD);
    GLOADF(1, yA, yB, yC, yD);
    GLOADF(2, zA, zB, zC, zD);
    GLOADF(3, uA, uB, uC, uD);

    // phase 0: groups 0,1 landed (16 in flight -> retire oldest 8)
    W(8);
    PROCG(0, false, xA, xB, xC, xD);
    PROCG(1, false, yA, yB, yC, yD);
    GLOADF(4, xA, xB, xC, xD);
    GLOADF(5, yA, yB, yC, yD);
    // phase 1: groups 2,3 landed
    W(8);
    PROCG(2, false, zA, zB, zC, zD);
    PROCG(3, false, uA, uB, uC, uD);
    GLOADF(6, zA, zB, zC, zD);
    GLOADF(7, uA, uB, uC, uD);
    // phase 2: groups 4,5 landed
    W(8);
    PROCG(4, false, xA, xB, xC, xD);
    PROCG(5, false, yA, yB, yC, yD);
    GLOADF(8, xA, xB, xC, xD);
    GLOADS(9, yA, yB, yC, yD);
    // phase 3: groups 6,7 landed
    W(8);
    PROCG(6, false, zA, zB, zC, zD);
    PROCG(7, false, uA, uB, uC, uD);
    // phase 4: groups 8,9 landed; nothing in flight after (no R11 hazard)
    W(0);
    PROCG(8, false, xA, xB, xC, xD);
    PROCG(9, true,  yA, yB, yC, yD);

#undef GLOADF
#undef GLOADS
#undef W
#undef PROCG

    // wave butterfly: merge sorted 5-lists across all 64 lanes
    #pragma unroll
    for (int off = 1; off < 64; off <<= 1) {
        const u64 b0 = __shfl_xor(k0, off);
        const u64 b1 = __shfl_xor(k1, off);
        const u64 b2 = __shfl_xor(k2, off);
        const u64 b3 = __shfl_xor(k3, off);
        const u64 b4 = __shfl_xor(k4, off);
        u64 m0_ = k0 < b4 ? k0 : b4;
        u64 m1_ = k1 < b3 ? k1 : b3;
        u64 m2_ = k2 < b2 ? k2 : b2;
        u64 m3_ = k3 < b1 ? k3 : b1;
        u64 m4_ = k4 < b0 ? k4 : b0;
        CE(m0_, m1_); CE(m3_, m4_); CE(m2_, m4_); CE(m2_, m3_); CE(m1_, m4_);
        CE(m0_, m3_); CE(m0_, m2_); CE(m1_, m3_); CE(m1_, m2_);
        k0 = m0_; k1 = m1_; k2 = m2_; k3 = m3_; k4 = m4_;
    }

    // cross-wave merge via LDS: per gt, 2 sorted 5-lists -> final 5
    __shared__ u64 lds[WAVES][TOPK];
    if (lane == 0) {
        lds[wid][0] = k0; lds[wid][1] = k1; lds[wid][2] = k2;
        lds[wid][3] = k3; lds[wid][4] = k4;
    }
    __syncthreads();

    if (threadIdx.x < 2) {
        const int which = threadIdx.x;       // gt0 / gt1
        if (which == 0 || has1) {
            const int mm = m0 + which;
            int h0 = 0, h1 = 0;
            const int base = (b * NG + mm) * TOPK;
            #pragma unroll
            for (int r = 0; r < TOPK; ++r) {
                const u64 v0 = lds[which * 2][h0];
                const u64 v1 = lds[which * 2 + 1][h1];
                const bool t = v0 < v1;
                const u64 best = t ? v0 : v1;
                h0 += t; h1 += !t;
                out_pred[base + r] = (int)(unsigned)(best & 0xFFFFFFFFu);
                out_gt[base + r]   = mm;
            }
        }
    }
}

extern "C" void kernel_launch(void* const* d_in, const int* in_sizes, int n_in,
                              void* d_out, int out_size, void* d_ws, size_t ws_size,
                              hipStream_t stream) {
    const float* pred_box = (const float*)d_in[0];   // [B, NP, 4]
    const float* gt_box   = (const float*)d_in[2];   // [B, NG, 4]

    const int NP = 5000;
    const int B  = in_sizes[1] / NP;                 // pred_obj is [B, NP]
    const int NG = in_sizes[3] / B;                  // gt_obj is [B, NG]

    int* out_pred = (int*)d_out;
    int* out_gt   = out_pred + B * NG * TOPK;

    const int pairsPerB = (NG + 1) >> 1;
    const int blocks = B * pairsPerB;                // one block per gt-pair
    hipLaunchKernelGGL(matcher_topk_kernel, dim3(blocks), dim3(64 * WAVES), 0, stream,
                       pred_box, gt_box, out_pred, out_gt, B, NP, NG);
}